// Round 2
// baseline (159.102 us; speedup 1.0000x reference)
//
#include <hip/hip_runtime.h>
#include <math.h>

#define D 128
#define K 16

// Kernel 1: per-edge attention score e = softplus(dot(zf, w[0:128]) + dot(zo, w[128:256]))
// Stored to e_pad[edge+1]; e_pad[0] = 0 (padding slot, matches reference zero-prepend).
// Each 32-lane half-wave handles one edge: 32 lanes x float4 = 128 floats.
__global__ __launch_bounds__(256) void edge_scores(
    const float* __restrict__ zf, const float* __restrict__ zo,
    const float* __restrict__ w, float* __restrict__ e_pad, int E)
{
    if (blockIdx.x == 0 && threadIdx.x == 0) e_pad[0] = 0.f;

    int gw   = (blockIdx.x * blockDim.x + threadIdx.x) >> 6;  // global wave id
    int lane = threadIdx.x & 63;
    int half = lane >> 5;
    int sub  = lane & 31;
    long long e = (long long)gw * 2 + half;
    if (e >= E) return;

    float4 wf = *(const float4*)(w + 4 * sub);        // weights for z_feature half
    float4 wo = *(const float4*)(w + D + 4 * sub);    // weights for z_others half

    const float4 a = *(const float4*)(zf + e * D + 4 * sub);
    const float4 b = *(const float4*)(zo + e * D + 4 * sub);

    float p = a.x * wf.x + a.y * wf.y + a.z * wf.z + a.w * wf.w
            + b.x * wo.x + b.y * wo.y + b.z * wo.z + b.w * wo.w;

    // reduce within the 32-lane half (xor offsets stay inside the half)
    #pragma unroll
    for (int off = 16; off; off >>= 1) p += __shfl_xor(p, off);

    if (sub == 0) {
        // stable softplus == logaddexp(p, 0)
        float sp = fmaxf(p, 0.f) + log1pf(expf(-fabsf(p)));
        e_pad[e + 1] = sp;
    }
}

// Kernel 2: one 64-lane wave per output row (row 0 = zeros, row n+1 = f_up[n]).
// Lanes 0..15 gather scope indices + e values; 16-lane shuffle softmax; then
// 16 broadcast iterations of coalesced 512B row-gathers from z_others.
__global__ __launch_bounds__(256) void aggregate(
    const int* __restrict__ scope, const float* __restrict__ zo,
    const float* __restrict__ e_pad, float* __restrict__ out, int N)
{
    int gw   = (blockIdx.x * blockDim.x + threadIdx.x) >> 6;
    int lane = threadIdx.x & 63;
    if (gw > N) return;

    if (gw == 0) {
        // zero-seeded first output row
        *(float2*)(out + 2 * lane) = make_float2(0.f, 0.f);
        return;
    }
    int n = gw - 1;

    int   idx = 0;
    float ev  = 0.f;
    if (lane < K) {
        idx = scope[(size_t)n * K + lane];        // 0 == padding (int32 on device)
        ev  = e_pad[idx];                         // e_pad[0] == 0
    }

    // masked softmax over K, replicating reference semantics:
    // logits = mask ? e : -1e30 ; alpha = softmax(logits) ; alpha = mask ? alpha : 0
    float logit = (ev != 0.f) ? ev : -1e30f;
    float m = logit;
    #pragma unroll
    for (int off = 8; off; off >>= 1) m = fmaxf(m, __shfl_xor(m, off));
    float ex = expf(logit - m);
    float s = ex;
    #pragma unroll
    for (int off = 8; off; off >>= 1) s += __shfl_xor(s, off);
    float alpha = (ev != 0.f) ? (ex / s) : 0.f;

    // weighted neighbor sum: each lane owns 2 of the 128 output features
    float2 acc = make_float2(0.f, 0.f);
    #pragma unroll
    for (int k = 0; k < K; ++k) {
        float a  = __shfl(alpha, k);   // broadcast from lane k (wave-uniform)
        int   id = __shfl(idx, k);
        if (a != 0.f) {                // wave-uniform: skip padding / masked rows
            float2 v = *(const float2*)(zo + (size_t)(id - 1) * D + 2 * lane);
            acc.x += a * v.x;
            acc.y += a * v.y;
        }
    }
    *(float2*)(out + (size_t)gw * D + 2 * lane) = acc;
}

extern "C" void kernel_launch(void* const* d_in, const int* in_sizes, int n_in,
                              void* d_out, int out_size, void* d_ws, size_t ws_size,
                              hipStream_t stream) {
    const float* zf    = (const float*)d_in[0];
    const float* zo    = (const float*)d_in[1];
    const int*   scope = (const int*)d_in[2];     // harness passes integers as int32
    const float* w     = (const float*)d_in[3];
    float*       out   = (float*)d_out;

    int E = in_sizes[0] / D;
    int N = in_sizes[2] / K;

    float* e_pad = (float*)d_ws;  // (E+1) floats = ~2 MB

    // Kernel 1: 2 edges per wave, 4 waves per block -> 8 edges per block
    int waves1  = (E + 1) / 2;
    int blocks1 = (waves1 + 3) / 4;
    edge_scores<<<blocks1, 256, 0, stream>>>(zf, zo, w, e_pad, E);

    // Kernel 2: one wave per output row (N+1 rows)
    int waves2  = N + 1;
    int blocks2 = (waves2 + 3) / 4;
    aggregate<<<blocks2, 256, 0, stream>>>(scope, zo, e_pad, out, N);
}

// Round 5
// 146.380 us; speedup vs baseline: 1.0869x; 1.0869x over previous
//
#include <hip/hip_runtime.h>
#include <math.h>

#define D 128
#define K 16

typedef float f32x4 __attribute__((ext_vector_type(4)));
typedef float f32x2 __attribute__((ext_vector_type(2)));

// Kernel 1: per-edge attention score e = softplus(dot(zf, w[0:128]) + dot(zo, w[128:256]))
// Stored to e_pad[edge+1]; e_pad[0] = 0 (padding slot, matches reference zero-prepend).
// Each 32-lane half-wave handles one edge: 32 lanes x float4 = 128 floats.
// zf loads are NON-TEMPORAL: zf is never re-read, while zo is randomly
// re-gathered by kernel 2 — keep L3 (256 MB ~= sizeof zo) for zo.
__global__ __launch_bounds__(256) void edge_scores(
    const float* __restrict__ zf, const float* __restrict__ zo,
    const float* __restrict__ w, float* __restrict__ e_pad, int E)
{
    if (blockIdx.x == 0 && threadIdx.x == 0) e_pad[0] = 0.f;

    int gw   = (blockIdx.x * blockDim.x + threadIdx.x) >> 6;  // global wave id
    int lane = threadIdx.x & 63;
    int half = lane >> 5;
    int sub  = lane & 31;
    long long e = (long long)gw * 2 + half;
    if (e >= E) return;

    f32x4 wf = *(const f32x4*)(w + 4 * sub);        // weights for z_feature half
    f32x4 wo = *(const f32x4*)(w + D + 4 * sub);    // weights for z_others half

    f32x4 a = __builtin_nontemporal_load((const f32x4*)(zf + e * D + 4 * sub));
    f32x4 b = *(const f32x4*)(zo + e * D + 4 * sub);

    float p = a.x * wf.x + a.y * wf.y + a.z * wf.z + a.w * wf.w
            + b.x * wo.x + b.y * wo.y + b.z * wo.z + b.w * wo.w;

    // reduce within the 32-lane half (xor offsets stay inside the half)
    #pragma unroll
    for (int off = 16; off; off >>= 1) p += __shfl_xor(p, off);

    if (sub == 0) {
        // stable softplus == logaddexp(p, 0)
        float sp = fmaxf(p, 0.f) + log1pf(expf(-fabsf(p)));
        e_pad[e + 1] = sp;
    }
}

// Kernel 2: one 64-lane wave per output row (row 0 = zeros, row n+1 = f_up[n]).
// Lanes 0..15 gather scope indices + e values; 16-lane shuffle softmax; then
// 16 branch-free coalesced 512B row-gathers (all loads issued before the
// accumulate chain -> 16 loads in flight per wave).
__global__ __launch_bounds__(256) void aggregate(
    const int* __restrict__ scope, const float* __restrict__ zo,
    const float* __restrict__ e_pad, float* __restrict__ out, int N)
{
    int gw   = (blockIdx.x * blockDim.x + threadIdx.x) >> 6;
    int lane = threadIdx.x & 63;
    if (gw > N) return;

    if (gw == 0) {
        // zero-seeded first output row
        f32x2 z = {0.f, 0.f};
        __builtin_nontemporal_store(z, (f32x2*)(out + 2 * lane));
        return;
    }
    int n = gw - 1;

    int   idx = 0;
    float ev  = 0.f;
    if (lane < K) {
        idx = scope[(size_t)n * K + lane];        // 0 == padding (int32 on device)
        ev  = e_pad[idx];                         // e_pad[0] == 0
    }

    // masked softmax over K, replicating reference semantics:
    // logits = mask ? e : -1e30 ; alpha = softmax(logits) ; alpha = mask ? alpha : 0
    float logit = (ev != 0.f) ? ev : -1e30f;
    float m = logit;
    #pragma unroll
    for (int off = 8; off; off >>= 1) m = fmaxf(m, __shfl_xor(m, off));
    float ex = expf(logit - m);
    float s = ex;
    #pragma unroll
    for (int off = 8; off; off >>= 1) s += __shfl_xor(s, off);
    float alpha = (ev != 0.f) ? (ex / s) : 0.f;

    // Branch-free gather: padding (id==0, alpha==0) clamps to row 0 and
    // contributes 0. Loads all issued before the accumulate chain.
    f32x2 v[K];
    float aa[K];
    #pragma unroll
    for (int k = 0; k < K; ++k) {
        aa[k]   = __shfl(alpha, k);               // wave-uniform broadcast
        int id  = __shfl(idx, k);
        int row = (id > 0) ? (id - 1) : 0;
        v[k] = *(const f32x2*)(zo + (size_t)row * D + 2 * lane);
    }

    f32x2 acc = {0.f, 0.f};
    #pragma unroll
    for (int k = 0; k < K; ++k) {
        acc.x += aa[k] * v[k].x;
        acc.y += aa[k] * v[k].y;
    }
    __builtin_nontemporal_store(acc, (f32x2*)(out + (size_t)gw * D + 2 * lane));
}

extern "C" void kernel_launch(void* const* d_in, const int* in_sizes, int n_in,
                              void* d_out, int out_size, void* d_ws, size_t ws_size,
                              hipStream_t stream) {
    const float* zf    = (const float*)d_in[0];
    const float* zo    = (const float*)d_in[1];
    const int*   scope = (const int*)d_in[2];     // harness passes integers as int32
    const float* w     = (const float*)d_in[3];
    float*       out   = (float*)d_out;

    int E = in_sizes[0] / D;
    int N = in_sizes[2] / K;

    float* e_pad = (float*)d_ws;  // (E+1) floats = ~2 MB

    // Kernel 1: 2 edges per wave, 4 waves per block -> 8 edges per block
    int waves1  = (E + 1) / 2;
    int blocks1 = (waves1 + 3) / 4;
    edge_scores<<<blocks1, 256, 0, stream>>>(zf, zo, w, e_pad, E);

    // Kernel 2: one wave per output row (N+1 rows)
    int waves2  = N + 1;
    int blocks2 = (waves2 + 3) / 4;
    aggregate<<<blocks2, 256, 0, stream>>>(scope, zo, e_pad, out, N);
}